// Round 25
// baseline (1051.126 us; speedup 1.0000x reference)
//
#include <hip/hip_runtime.h>
#include <cstdint>

#define D     256
#define NB    32          // blocks
#define TPB   256         // threads per block
#define HS    8           // h-elements owned per block (D/NB)
#define NROW  32          // gate rows owned per block (4*HS)
#define MAXA  14
#define UNITS 12
#define NEGV  (-1e9f)

// ---- cross-block state: gen-parity double-buffered self-tagged qwords ----
// slot = (gen&1)*D + idx ; provably race-free (r24 theory)
__device__ unsigned long long g_Hq[2 * D];

__global__ void init_kernel() {
  int i = threadIdx.x;
  if (i < 2 * D) g_Hq[i] = 0ull;
}

__device__ __forceinline__ void qstore(unsigned long long* p, unsigned gen,
                                       float v) {
  unsigned long long q =
      ((unsigned long long)gen << 32) | (unsigned long long)__float_as_uint(v);
  __hip_atomic_store(p, q, __ATOMIC_RELAXED, __HIP_MEMORY_SCOPE_AGENT);
}

__device__ __forceinline__ float qpoll(unsigned long long* p, unsigned gen) {
  unsigned long long q;
  long spins = 0;
  for (;;) {
    q = __hip_atomic_load(p, __ATOMIC_RELAXED, __HIP_MEMORY_SCOPE_AGENT);
    if ((unsigned)(q >> 32) == gen) break;
    __builtin_amdgcn_s_sleep(1);
    if (++spins > 20000000L) break;   // bail only on bug (finite-time fail)
  }
  return __uint_as_float((unsigned)q);
}

__device__ __forceinline__ uint32_t rotl32(uint32_t v, uint32_t n) {
  return (v << n) | (v >> (32u - n));
}

// JAX threefry2x32 (20 rounds) — KAT-verified on-device (r7)
__device__ uint2 tf2x32(uint2 k, uint32_t x0, uint32_t x1) {
  uint32_t ks0 = k.x, ks1 = k.y, ks2 = 0x1BD11BDAu ^ ks0 ^ ks1;
  x0 += ks0; x1 += ks1;
#define TF4(a,b,c,d) \
  x0 += x1; x1 = rotl32(x1,(a)); x1 ^= x0; \
  x0 += x1; x1 = rotl32(x1,(b)); x1 ^= x0; \
  x0 += x1; x1 = rotl32(x1,(c)); x1 ^= x0; \
  x0 += x1; x1 = rotl32(x1,(d)); x1 ^= x0;
  TF4(13,15,26,6)  x0 += ks1; x1 += ks2 + 1u;
  TF4(17,29,16,24) x0 += ks2; x1 += ks0 + 2u;
  TF4(13,15,26,6)  x0 += ks0; x1 += ks1 + 3u;
  TF4(17,29,16,24) x0 += ks1; x1 += ks2 + 4u;
  TF4(13,15,26,6)  x0 += ks2; x1 += ks0 + 5u;
#undef TF4
  return make_uint2(x0, x1);
}

// JAX uniform -> gumbel, bit-exact (verified vs ref arcs, r19)
__device__ __forceinline__ float gumbelf(uint32_t bits) {
  float f = __uint_as_float((bits >> 9) | 0x3f800000u) - 1.0f;
  const float tiny = 1.17549435082228751e-38f;
  float u = fmaxf(tiny, f);
  return -logf(-logf(u));
}

// XLA LogisticExpander form
__device__ __forceinline__ float sigm(float x) {
  return 0.5f + 0.5f * tanhf(0.5f * x);
}

__global__ void __launch_bounds__(TPB) ENAScontroller_21706764714567_kernel(
    const float* __restrict__ enc,   const float* __restrict__ Wih,
    const float* __restrict__ Whh,   const float* __restrict__ bih,
    const float* __restrict__ bhh,   const float* __restrict__ wsoft,
    const float* __restrict__ bsoft, const float* __restrict__ wa1,
    const float* __restrict__ wa2,   const float* __restrict__ vattn,
    float* __restrict__ out)
{
  const int b    = blockIdx.x;
  const int t    = threadIdx.x;
  const int lane = t & 63;
  const int wv_  = t >> 6;            // wave id 0..3

  unsigned hgen = 0;                  // uniform across all blocks/threads

  // ---- LDS (~56 KB) ----
  __shared__ float4 sWhh4[64 * NROW]; // 32 KB: own W_hh gate rows
  __shared__ __align__(16) float s_h[D];
  __shared__ float s_part[TPB];
  __shared__ float s_eW[9][NROW];
  __shared__ float s_aW[MAXA][NROW];
  __shared__ float s_aw1[MAXA][D];    // FULL aw1 rows (replicated) 14 KB
  __shared__ float s_t2f[D];          // full w2 @ h
  __shared__ float s_v[D];            // full v_attn
  __shared__ float s_red2[MAXA][32];  // attention partials (old layout)
  __shared__ float s_c[HS];
  __shared__ float s_bc[NROW];
  __shared__ float s_bsoft[8];
  __shared__ float s_log[16];
  __shared__ float s_z[16];
  __shared__ uint2 s_pair[2];
  __shared__ uint2 s_key;
  __shared__ int   s_sel;
  __shared__ float s_lp, s_ent;

  // ---------- init ----------
  for (int idx = t; idx < 64 * NROW; idx += TPB) {
    int kk = idx >> 5, j = idx & 31;
    int grow = (j >> 3) * D + b * HS + (j & 7);
    sWhh4[idx] = *(const float4*)&Whh[grow * D + kk * 4];
  }
  if (t < NROW) {
    int grow = (t >> 3) * D + b * HS + (t & 7);
    s_bc[t] = bih[grow] + bhh[grow];
  }
  s_v[t] = vattn[t];
  if (t < 8) s_bsoft[t] = bsoft[t];
  if (t < HS) s_c[t] = 0.f;
  s_h[t] = 0.f;                       // h0 = 0 locally
  if (t == 0) { s_lp = 0.f; s_ent = 0.f; }
  // PARTITIONABLE split(key(123)): newkey[i] = cipher(key, (0, i))
  if (t < 2) s_pair[t] = tf2x32(make_uint2(0u, 123u), 0u, (uint32_t)t);
  __syncthreads();
  const uint2 key1 = s_pair[0];
  const uint2 key2 = s_pair[1];

  for (int m = 0; m < 8; ++m) {
    int j = wv_ * 8 + m;
    int grow = wv_ * D + b * HS + m;
    float4 wrow = *(const float4*)&Wih[grow * D + lane * 4];
    for (int r = 0; r < 9; ++r) {
      float4 ev = *(const float4*)&enc[r * D + lane * 4];
      float x = wrow.x * ev.x + wrow.y * ev.y + wrow.z * ev.z + wrow.w * ev.w;
      #pragma unroll
      for (int s = 32; s; s >>= 1) x += __shfl_xor(x, s);
      if (lane == 0) s_eW[r][j] = x;
    }
  }
  __syncthreads();

  // LSTM split: PRE = matvec(old h) + gates + qstore; POST = poll new h.
  auto LSTM_PRE = [&](const float* xd) {
    {
      int j = t & 31, p = t >> 5;
      const float4* hp = (const float4*)s_h;
      float acc = 0.f;
      #pragma unroll
      for (int q = 0; q < 8; ++q) {
        int kk = p * 8 + q;
        float4 wvv = sWhh4[kk * 32 + j];
        float4 hv  = hp[kk];
        acc += wvv.x * hv.x + wvv.y * hv.y + wvv.z * hv.z + wvv.w * hv.w;
      }
      s_part[t] = acc;
    }
    __syncthreads();
    ++hgen;
    if (t < HS) {
      float gg[4];
      #pragma unroll
      for (int q = 0; q < 4; ++q) {
        int j = q * 8 + t;
        float s = s_bc[j] + xd[j];
        #pragma unroll
        for (int p = 0; p < 8; ++p) s += s_part[p * 32 + j];
        gg[q] = s;
      }
      float c2 = sigm(gg[1]) * s_c[t] + sigm(gg[0]) * tanhf(gg[2]);
      float hn = sigm(gg[3]) * tanhf(c2);
      s_c[t] = c2;
      qstore(&g_Hq[(hgen & 1) * D + b * HS + t], hgen, hn);
    }
    // NOTE: no barrier — caller may run "hidden" work that reads OLD s_h.
  };

  auto LSTM_POST = [&]() {
    __syncthreads();                  // everyone done reading old s_h
    float hv = qpoll(&g_Hq[(hgen & 1) * D + t], hgen);
    s_h[t] = hv;
    __syncthreads();
  };

  // full D-dim matvec dst = W @ s_h. Same summation nesting as r24 (bit-exact)
  // but unroll capped to keep VGPRs low (r24 fully unrolled -> 256 VGPR +
  // 7.4MB scratch spills; that was the regression).
  auto DOTFULL = [&](const float* __restrict__ W, float* dst) {
    const float4* W4 = (const float4*)W;
    const float4* hp = (const float4*)s_h;
    int j = t;
    float acc = 0.f;
    #pragma unroll 2
    for (int p = 0; p < 8; ++p) {
      float pp = 0.f;
      #pragma unroll
      for (int q = 0; q < 8; ++q) {
        int kk = p * 8 + q;
        float4 m4 = W4[j * 64 + kk];
        float4 hv = hp[kk];
        pp += m4.x * hv.x + m4.y * hv.y + m4.z * hv.z + m4.w * hv.w;
      }
      acc += pp;
    }
    dst[j] = acc;
    __syncthreads();
  };

  auto AWC = [&](int slot) {   // own W_ih rows @ s_h (anchor) — hidden work
    const float4* hp = (const float4*)s_h;
    for (int m = 0; m < 8; ++m) {
      int j = wv_ * 8 + m;
      int grow = wv_ * D + b * HS + m;
      float4 wrow = *(const float4*)&Wih[grow * D + lane * 4];
      float4 hv = hp[lane];
      float x = wrow.x * hv.x + wrow.y * hv.y + wrow.z * hv.z + wrow.w * hv.w;
      #pragma unroll
      for (int s = 32; s; s >>= 1) x += __shfl_xor(x, s);
      if (lane == 0) s_aW[slot][j] = x;
    }
    __syncthreads();
  };

  // replicated attention: full t2 locally, partials in OLD bit-exact layout
  auto ATTNL = [&]() {
    DOTFULL(wa2, s_t2f);
    for (int idx = t; idx < MAXA * 32; idx += TPB) {
      int a = idx >> 5, bb = idx & 31;
      float pa = 0.f;
      #pragma unroll
      for (int d2 = 0; d2 < 8; ++d2) {
        int d = bb * 8 + d2;
        pa += tanhf(s_aw1[a][d] + s_t2f[d]) * s_v[d];
      }
      s_red2[a][bb] = pa;
    }
    __syncthreads();
  };

  auto ALOGITS = [&](int u) {
    if (t < MAXA) {
      float l = 0.f;
      #pragma unroll
      for (int bb = 0; bb < NB; ++bb) l += s_red2[t][bb];
      l = 1.1f * tanhf(l / 5.0f);
      s_log[t] = (t < u) ? l : NEGV;
    }
    __syncthreads();
  };

  auto OLOGITS = [&](bool useBias) {
    if (t < 64) {
      int j = t & 7, p = t >> 3;
      const float4* hp = (const float4*)s_h;
      float acc = 0.f;
      #pragma unroll
      for (int q = 0; q < 8; ++q) {
        int kk = p * 8 + q;
        float4 m4 = *(const float4*)&wsoft[j * D + kk * 4];
        float4 hv = hp[kk];
        acc += m4.x * hv.x + m4.y * hv.y + m4.z * hv.z + m4.w * hv.w;
      }
      s_part[t] = acc;
    }
    __syncthreads();
    if (t < 8) {
      float s = 0.f;
      #pragma unroll
      for (int p = 0; p < 8; ++p) s += s_part[p * 8 + t];
      float l = s + s_bsoft[t];
      l = 1.1f * tanhf(l / 5.0f);
      if (useBias) l += (t < 2 ? 0.25f : -0.25f);
      s_log[t] = l;
    }
    __syncthreads();
  };

  // PARTITIONABLE sampling — verified bit-exact vs reference arcs (r19)
  auto SAMPLE = [&](int N) -> int {
    if (t < 2) s_pair[t] = tf2x32(s_key, 0u, (uint32_t)t);
    __syncthreads();
    uint2 sub = s_pair[1];
    if (t == 0) s_key = s_pair[0];
    if (t < N) {
      uint2 e = tf2x32(sub, 0u, (uint32_t)t);
      s_z[t] = s_log[t] + gumbelf(e.x ^ e.y);
    }
    __syncthreads();
    if (t == 0) {
      int bi = 0; float bz = s_z[0];
      for (int a = 1; a < N; ++a) if (s_z[a] > bz) { bz = s_z[a]; bi = a; }
      float m = s_log[0];
      for (int a = 1; a < N; ++a) m = fmaxf(m, s_log[a]);
      float ssum = 0.f, sdl = 0.f;
      for (int a = 0; a < N; ++a) {
        float d2 = s_log[a] - m;
        float e2 = expf(d2);
        ssum += e2; sdl += e2 * d2;
      }
      float ls = logf(ssum);
      s_lp  += -(s_log[bi] - m - ls);
      s_ent += ls - sdl / ssum;
      s_sel = bi;
    }
    __syncthreads();
    return s_sel;
  };

  // ---------- two samplers ----------
  for (int smp = 0; smp < 2; ++smp) {
    for (int idx = t; idx < MAXA * NROW; idx += TPB) (&s_aW[0][0])[idx]  = 0.f;
    for (int idx = t; idx < MAXA * D;    idx += TPB) (&s_aw1[0][0])[idx] = 0.f;
    if (t == 0) s_key = (smp == 0) ? key1 : key2;
    __syncthreads();

    // seeds (aw1[0] from h-after-seed1, hidden under seed-2's exchange)
    LSTM_PRE(s_eW[0]);
    LSTM_POST();
    LSTM_PRE(s_eW[0]);
    DOTFULL(wa1, s_aw1[0]);           // hidden: uses pre-exchange s_h
    LSTM_POST();

    bool useBias = (smp == 0);
    for (int u = 2; u < 2 + UNITS; ++u) {
      // anchor work hidden under the unit's first exchange
      LSTM_PRE(s_eW[0]);
      DOTFULL(wa1, s_aw1[u - 1]);     // hidden (pre-exchange s_h = anchor h)
      if (u > 2) AWC(u - 1);          // hidden
      LSTM_POST();

      ATTNL(); ALOGITS(u);
      int i1 = SAMPLE(MAXA);
      LSTM_PRE(s_aW[i1]); LSTM_POST();

      ATTNL(); ALOGITS(u);
      int i2 = SAMPLE(MAXA);
      LSTM_PRE(s_aW[i2]); LSTM_POST();

      OLOGITS(useBias);
      int o1 = SAMPLE(8);
      LSTM_PRE(s_eW[o1 + 1]); LSTM_POST();

      OLOGITS(useBias);
      int o2 = SAMPLE(8);
      LSTM_PRE(s_eW[o2 + 1]); LSTM_POST();

      if (b == 0 && t == 0) {
        int base = smp * 48 + (u - 2) * 4;
        out[base + 0] = (float)i1;   // harness reads float32 (r19)
        out[base + 1] = (float)o1;
        out[base + 2] = (float)i2;
        out[base + 3] = (float)o2;
      }
    }
  }
  if (b == 0 && t == 0) {
    out[96] = s_lp;
    out[97] = s_ent;
  }
}

extern "C" __attribute__((visibility("default")))
void kernel_launch(void* const* d_in, const int* in_sizes, int n_in,
                   void* d_out, int out_size, void* d_ws, size_t ws_size,
                   hipStream_t stream) {
  const float* enc   = (const float*)d_in[0];
  const float* Wih   = (const float*)d_in[1];
  const float* Whh   = (const float*)d_in[2];
  const float* bih   = (const float*)d_in[3];
  const float* bhh   = (const float*)d_in[4];
  const float* wsoft = (const float*)d_in[5];
  const float* bsoft = (const float*)d_in[6];
  const float* wa1   = (const float*)d_in[7];
  const float* wa2   = (const float*)d_in[8];
  const float* vattn = (const float*)d_in[9];
  float* out = (float*)d_out;

  init_kernel<<<dim3(1), dim3(512), 0, stream>>>();
  ENAScontroller_21706764714567_kernel<<<dim3(NB), dim3(TPB), 0, stream>>>(
      enc, Wih, Whh, bih, bhh, wsoft, bsoft, wa1, wa2, vattn, out);
}

// Round 26
// 727.210 us; speedup vs baseline: 1.4454x; 1.4454x over previous
//
#include <hip/hip_runtime.h>
#include <cstdint>

#define D     256
#define NB    32          // blocks
#define TPB   256         // threads per block
#define HS    8           // h-elements owned per block (D/NB)
#define NROW  32          // gate rows owned per block (4*HS)
#define MAXA  14
#define UNITS 12
#define NEGV  (-1e9f)

// ---- cross-block state: gen-parity double-buffered self-tagged qwords ----
__device__ unsigned long long g_Hq[2 * D];        // h slots
__device__ unsigned long long g_PartQ[2 * NB*16]; // attention partial slots

__global__ void init_kernel() {
  int i = threadIdx.x;
  if (i < 2 * D) g_Hq[i] = 0ull;
  for (int s = i; s < 2 * NB * 16; s += 1024) g_PartQ[s] = 0ull;
}

__device__ __forceinline__ void qstore(unsigned long long* p, unsigned gen,
                                       float v) {
  unsigned long long q =
      ((unsigned long long)gen << 32) | (unsigned long long)__float_as_uint(v);
  __hip_atomic_store(p, q, __ATOMIC_RELAXED, __HIP_MEMORY_SCOPE_AGENT);
}

__device__ __forceinline__ float qpoll(unsigned long long* p, unsigned gen) {
  unsigned long long q;
  long spins = 0;
  for (;;) {
    q = __hip_atomic_load(p, __ATOMIC_RELAXED, __HIP_MEMORY_SCOPE_AGENT);
    if ((unsigned)(q >> 32) == gen) break;
    __builtin_amdgcn_s_sleep(1);
    if (++spins > 20000000L) break;   // bail only on bug
  }
  return __uint_as_float((unsigned)q);
}

__device__ __forceinline__ uint32_t rotl32(uint32_t v, uint32_t n) {
  return (v << n) | (v >> (32u - n));
}

// JAX threefry2x32 (20 rounds) — KAT-verified on-device (r7)
__device__ uint2 tf2x32(uint2 k, uint32_t x0, uint32_t x1) {
  uint32_t ks0 = k.x, ks1 = k.y, ks2 = 0x1BD11BDAu ^ ks0 ^ ks1;
  x0 += ks0; x1 += ks1;
#define TF4(a,b,c,d) \
  x0 += x1; x1 = rotl32(x1,(a)); x1 ^= x0; \
  x0 += x1; x1 = rotl32(x1,(b)); x1 ^= x0; \
  x0 += x1; x1 = rotl32(x1,(c)); x1 ^= x0; \
  x0 += x1; x1 = rotl32(x1,(d)); x1 ^= x0;
  TF4(13,15,26,6)  x0 += ks1; x1 += ks2 + 1u;
  TF4(17,29,16,24) x0 += ks2; x1 += ks0 + 2u;
  TF4(13,15,26,6)  x0 += ks0; x1 += ks1 + 3u;
  TF4(17,29,16,24) x0 += ks1; x1 += ks2 + 4u;
  TF4(13,15,26,6)  x0 += ks2; x1 += ks0 + 5u;
#undef TF4
  return make_uint2(x0, x1);
}

// JAX uniform -> gumbel, bit-exact (verified vs ref arcs, r19)
__device__ __forceinline__ float gumbelf(uint32_t bits) {
  float f = __uint_as_float((bits >> 9) | 0x3f800000u) - 1.0f;
  const float tiny = 1.17549435082228751e-38f;
  float u = fmaxf(tiny, f);
  return -logf(-logf(u));
}

// XLA LogisticExpander form
__device__ __forceinline__ float sigm(float x) {
  return 0.5f + 0.5f * tanhf(0.5f * x);
}

__global__ void __launch_bounds__(TPB) ENAScontroller_21706764714567_kernel(
    const float* __restrict__ enc,   const float* __restrict__ Wih,
    const float* __restrict__ Whh,   const float* __restrict__ bih,
    const float* __restrict__ bhh,   const float* __restrict__ wsoft,
    const float* __restrict__ bsoft, const float* __restrict__ wa1,
    const float* __restrict__ wa2,   const float* __restrict__ vattn,
    float* __restrict__ out)
{
  const int b    = blockIdx.x;
  const int t    = threadIdx.x;
  const int lane = t & 63;
  const int wv_  = t >> 6;            // wave id 0..3

  unsigned hgen = 0;                  // uniform across all blocks/threads
  unsigned pgen = 0;

  // ---- LDS (~55 KB) ----
  __shared__ float4 sWhh4[64 * NROW]; // 32 KB
  __shared__ float4 sWa1p[64 * HS];   // 8 KB (own wa1 rows)
  __shared__ float4 sWa2p[64 * HS];   // 8 KB (own wa2 rows)
  __shared__ __align__(16) float s_h[D];
  __shared__ float s_part[TPB];
  __shared__ float s_pp[NB * 16];     // gathered attention partials
  __shared__ float s_eW[9][NROW];
  __shared__ float s_aW[MAXA][NROW];
  __shared__ float s_aw1[MAXA][HS];   // own aw1 slice
  __shared__ float s_t2[HS];
  __shared__ float s_vs[HS];
  __shared__ float s_c[HS];
  __shared__ float s_bc[NROW];
  __shared__ float s_bsoft[8];
  __shared__ float s_log[16];
  __shared__ float s_z[16];
  __shared__ uint2 s_pair[2];
  __shared__ uint2 s_key;
  __shared__ int   s_sel;
  __shared__ float s_lp, s_ent;

  // ---------- init ----------
  for (int idx = t; idx < 64 * NROW; idx += TPB) {
    int kk = idx >> 5, j = idx & 31;
    int grow = (j >> 3) * D + b * HS + (j & 7);
    sWhh4[idx] = *(const float4*)&Whh[grow * D + kk * 4];
  }
  for (int idx = t; idx < 64 * HS; idx += TPB) {
    int kk = idx >> 3, j = idx & 7;
    sWa1p[idx] = *(const float4*)&wa1[(b * HS + j) * D + kk * 4];
    sWa2p[idx] = *(const float4*)&wa2[(b * HS + j) * D + kk * 4];
  }
  if (t < NROW) {
    int grow = (t >> 3) * D + b * HS + (t & 7);
    s_bc[t] = bih[grow] + bhh[grow];
  }
  if (t < HS) {
    s_vs[t] = vattn[b * HS + t];
    s_c[t] = 0.f;
  }
  if (t < 8) s_bsoft[t] = bsoft[t];
  s_h[t] = 0.f;                       // h0 = 0 locally
  if (t == 0) { s_lp = 0.f; s_ent = 0.f; }
  // PARTITIONABLE split(key(123)): newkey[i] = cipher(key, (0, i))
  if (t < 2) s_pair[t] = tf2x32(make_uint2(0u, 123u), 0u, (uint32_t)t);
  __syncthreads();
  const uint2 key1 = s_pair[0];
  const uint2 key2 = s_pair[1];

  for (int m = 0; m < 8; ++m) {
    int j = wv_ * 8 + m;
    int grow = wv_ * D + b * HS + m;
    float4 wrow = *(const float4*)&Wih[grow * D + lane * 4];
    for (int r = 0; r < 9; ++r) {
      float4 ev = *(const float4*)&enc[r * D + lane * 4];
      float x = wrow.x * ev.x + wrow.y * ev.y + wrow.z * ev.z + wrow.w * ev.w;
      #pragma unroll
      for (int s = 32; s; s >>= 1) x += __shfl_xor(x, s);
      if (lane == 0) s_eW[r][j] = x;
    }
  }
  __syncthreads();

  // LSTM split: PRE = matvec(old h)+gates+qstore; POST = wave0 polls new h.
  auto LSTM_PRE = [&](const float* xd) {
    {
      int j = t & 31, p = t >> 5;
      const float4* hp = (const float4*)s_h;
      float acc = 0.f;
      #pragma unroll
      for (int q = 0; q < 8; ++q) {
        int kk = p * 8 + q;
        float4 wvv = sWhh4[kk * 32 + j];
        float4 hv  = hp[kk];
        acc += wvv.x * hv.x + wvv.y * hv.y + wvv.z * hv.z + wvv.w * hv.w;
      }
      s_part[t] = acc;
    }
    __syncthreads();
    ++hgen;
    if (t < HS) {
      float gg[4];
      #pragma unroll
      for (int q = 0; q < 4; ++q) {
        int j = q * 8 + t;
        float s = s_bc[j] + xd[j];
        #pragma unroll
        for (int p = 0; p < 8; ++p) s += s_part[p * 32 + j];
        gg[q] = s;
      }
      float c2 = sigm(gg[1]) * s_c[t] + sigm(gg[0]) * tanhf(gg[2]);
      float hn = sigm(gg[3]) * tanhf(c2);
      s_c[t] = c2;
      qstore(&g_Hq[(hgen & 1) * D + b * HS + t], hgen, hn);
    }
    // no barrier: hidden work below reads OLD s_h (safe: parity slots)
  };

  auto LSTM_POST = [&]() {
    __syncthreads();                  // everyone done reading old s_h
    if (t < 64) {                     // wave0 only: 4 slots each (contention)
      unsigned long long* base2 = &g_Hq[(hgen & 1) * D];
      #pragma unroll
      for (int k = 0; k < 4; ++k) {
        int slot = t * 4 + k;
        s_h[slot] = qpoll(&base2[slot], hgen);
      }
    }
    __syncthreads();
  };

  auto DOT8 = [&](const float4* M, float* dst) {   // dst[j] = M_rows . s_h
    if (t < 64) {
      int j = t & 7, p = t >> 3;
      const float4* hp = (const float4*)s_h;
      float acc = 0.f;
      #pragma unroll
      for (int q = 0; q < 8; ++q) {
        int kk = p * 8 + q;
        float4 m4 = M[kk * 8 + j];
        float4 hv = hp[kk];
        acc += m4.x * hv.x + m4.y * hv.y + m4.z * hv.z + m4.w * hv.w;
      }
      s_part[t] = acc;
    }
    __syncthreads();
    if (t < 8) {
      float s = 0.f;
      #pragma unroll
      for (int p = 0; p < 8; ++p) s += s_part[p * 8 + t];
      dst[t] = s;
    }
    __syncthreads();
  };

  auto AWC = [&](int slot) {   // own W_ih rows @ s_h (anchor) — hidden work
    const float4* hp = (const float4*)s_h;
    for (int m = 0; m < 8; ++m) {
      int j = wv_ * 8 + m;
      int grow = wv_ * D + b * HS + m;
      float4 wrow = *(const float4*)&Wih[grow * D + lane * 4];
      float4 hv = hp[lane];
      float x = wrow.x * hv.x + wrow.y * hv.y + wrow.z * hv.z + wrow.w * hv.w;
      #pragma unroll
      for (int s = 32; s; s >>= 1) x += __shfl_xor(x, s);
      if (lane == 0) s_aW[slot][j] = x;
    }
    __syncthreads();
  };

  // attention: own-slice t2, own 14 partials -> exchange -> wave0 gathers
  auto ATTN = [&]() {
    DOT8(sWa2p, s_t2);
    ++pgen;
    if (t < MAXA) {
      float pa = 0.f;
      #pragma unroll
      for (int d2 = 0; d2 < HS; ++d2)
        pa += tanhf(s_aw1[t][d2] + s_t2[d2]) * s_vs[d2];
      qstore(&g_PartQ[(pgen & 1) * (NB * 16) + b * 16 + t], pgen, pa);
    }
    if (t < 64) {
      unsigned long long* base2 = &g_PartQ[(pgen & 1) * (NB * 16)];
      for (int s = t; s < NB * 16; s += 64)
        if ((s & 15) < MAXA) s_pp[s] = qpoll(&base2[s], pgen);
    }
    __syncthreads();
  };

  auto ALOGITS = [&](int u) {
    if (t < MAXA) {
      float l = 0.f;
      #pragma unroll
      for (int bb = 0; bb < NB; ++bb) l += s_pp[bb * 16 + t];
      l = 1.1f * tanhf(l / 5.0f);
      s_log[t] = (t < u) ? l : NEGV;
    }
    __syncthreads();
  };

  auto OLOGITS = [&](bool useBias) {
    if (t < 64) {
      int j = t & 7, p = t >> 3;
      const float4* hp = (const float4*)s_h;
      float acc = 0.f;
      #pragma unroll
      for (int q = 0; q < 8; ++q) {
        int kk = p * 8 + q;
        float4 m4 = *(const float4*)&wsoft[j * D + kk * 4];
        float4 hv = hp[kk];
        acc += m4.x * hv.x + m4.y * hv.y + m4.z * hv.z + m4.w * hv.w;
      }
      s_part[t] = acc;
    }
    __syncthreads();
    if (t < 8) {
      float s = 0.f;
      #pragma unroll
      for (int p = 0; p < 8; ++p) s += s_part[p * 8 + t];
      float l = s + s_bsoft[t];
      l = 1.1f * tanhf(l / 5.0f);
      if (useBias) l += (t < 2 ? 0.25f : -0.25f);
      s_log[t] = l;
    }
    __syncthreads();
  };

  // PARTITIONABLE sampling — verified bit-exact vs reference arcs (r19)
  auto SAMPLE = [&](int N) -> int {
    if (t < 2) s_pair[t] = tf2x32(s_key, 0u, (uint32_t)t);
    __syncthreads();
    uint2 sub = s_pair[1];
    if (t == 0) s_key = s_pair[0];
    if (t < N) {
      uint2 e = tf2x32(sub, 0u, (uint32_t)t);
      s_z[t] = s_log[t] + gumbelf(e.x ^ e.y);
    }
    __syncthreads();
    if (t == 0) {
      int bi = 0; float bz = s_z[0];
      for (int a = 1; a < N; ++a) if (s_z[a] > bz) { bz = s_z[a]; bi = a; }
      float m = s_log[0];
      for (int a = 1; a < N; ++a) m = fmaxf(m, s_log[a]);
      float ssum = 0.f, sdl = 0.f;
      for (int a = 0; a < N; ++a) {
        float d2 = s_log[a] - m;
        float e2 = expf(d2);
        ssum += e2; sdl += e2 * d2;
      }
      float ls = logf(ssum);
      s_lp  += -(s_log[bi] - m - ls);
      s_ent += ls - sdl / ssum;
      s_sel = bi;
    }
    __syncthreads();
    return s_sel;
  };

  // ---------- two samplers ----------
  for (int smp = 0; smp < 2; ++smp) {
    for (int idx = t; idx < MAXA * NROW; idx += TPB) (&s_aW[0][0])[idx]  = 0.f;
    for (int idx = t; idx < MAXA * HS;   idx += TPB) (&s_aw1[0][0])[idx] = 0.f;
    if (t == 0) s_key = (smp == 0) ? key1 : key2;
    __syncthreads();

    // seeds (aw1[0] from h-after-seed1, hidden under seed-2's exchange)
    LSTM_PRE(s_eW[0]);
    LSTM_POST();
    LSTM_PRE(s_eW[0]);
    DOT8(sWa1p, s_aw1[0]);            // hidden: reads pre-exchange s_h
    LSTM_POST();

    bool useBias = (smp == 0);
    for (int u = 2; u < 2 + UNITS; ++u) {
      // anchor work hidden under the unit's first exchange
      LSTM_PRE(s_eW[0]);
      DOT8(sWa1p, s_aw1[u - 1]);      // hidden (pre-exchange s_h = anchor h)
      if (u > 2) AWC(u - 1);          // hidden
      LSTM_POST();

      ATTN(); ALOGITS(u);
      int i1 = SAMPLE(MAXA);
      LSTM_PRE(s_aW[i1]); LSTM_POST();

      ATTN(); ALOGITS(u);
      int i2 = SAMPLE(MAXA);
      LSTM_PRE(s_aW[i2]); LSTM_POST();

      OLOGITS(useBias);
      int o1 = SAMPLE(8);
      LSTM_PRE(s_eW[o1 + 1]); LSTM_POST();

      OLOGITS(useBias);
      int o2 = SAMPLE(8);
      LSTM_PRE(s_eW[o2 + 1]); LSTM_POST();

      if (b == 0 && t == 0) {
        int base = smp * 48 + (u - 2) * 4;
        out[base + 0] = (float)i1;   // harness reads float32 (r19)
        out[base + 1] = (float)o1;
        out[base + 2] = (float)i2;
        out[base + 3] = (float)o2;
      }
    }
  }
  if (b == 0 && t == 0) {
    out[96] = s_lp;
    out[97] = s_ent;
  }
}

extern "C" __attribute__((visibility("default")))
void kernel_launch(void* const* d_in, const int* in_sizes, int n_in,
                   void* d_out, int out_size, void* d_ws, size_t ws_size,
                   hipStream_t stream) {
  const float* enc   = (const float*)d_in[0];
  const float* Wih   = (const float*)d_in[1];
  const float* Whh   = (const float*)d_in[2];
  const float* bih   = (const float*)d_in[3];
  const float* bhh   = (const float*)d_in[4];
  const float* wsoft = (const float*)d_in[5];
  const float* bsoft = (const float*)d_in[6];
  const float* wa1   = (const float*)d_in[7];
  const float* wa2   = (const float*)d_in[8];
  const float* vattn = (const float*)d_in[9];
  float* out = (float*)d_out;

  init_kernel<<<dim3(1), dim3(1024), 0, stream>>>();
  ENAScontroller_21706764714567_kernel<<<dim3(NB), dim3(TPB), 0, stream>>>(
      enc, Wih, Whh, bih, bhh, wsoft, bsoft, wa1, wa2, vattn, out);
}

// Round 27
// 590.131 us; speedup vs baseline: 1.7812x; 1.2323x over previous
//
#include <hip/hip_runtime.h>
#include <cstdint>

#define D     256
#define NB    32          // blocks
#define TPB   256         // threads per block
#define HS    8           // h-elements owned per block (D/NB)
#define NROW  32          // gate rows owned per block (4*HS)
#define MAXA  14
#define UNITS 12
#define NEGV  (-1e9f)

// ---- cross-block state: gen-parity double-buffered self-tagged qwords ----
__device__ unsigned long long g_Hq[2 * D];        // h slots
__device__ unsigned long long g_PartQ[2 * NB*16]; // attention partial slots

__global__ void init_kernel() {
  int i = threadIdx.x;
  if (i < 2 * D) g_Hq[i] = 0ull;
  if (i < 2 * NB * 16) g_PartQ[i] = 0ull;
}

__device__ __forceinline__ void qstore(unsigned long long* p, unsigned gen,
                                       float v) {
  unsigned long long q =
      ((unsigned long long)gen << 32) | (unsigned long long)__float_as_uint(v);
  __hip_atomic_store(p, q, __ATOMIC_RELAXED, __HIP_MEMORY_SCOPE_AGENT);
}

__device__ __forceinline__ float qpoll(unsigned long long* p, unsigned gen) {
  unsigned long long q;
  long spins = 0;
  for (;;) {
    q = __hip_atomic_load(p, __ATOMIC_RELAXED, __HIP_MEMORY_SCOPE_AGENT);
    if ((unsigned)(q >> 32) == gen) break;
    __builtin_amdgcn_s_sleep(1);
    if (++spins > 20000000L) break;   // bail only on bug
  }
  return __uint_as_float((unsigned)q);
}

__device__ __forceinline__ uint32_t rotl32(uint32_t v, uint32_t n) {
  return (v << n) | (v >> (32u - n));
}

// JAX threefry2x32 (20 rounds) — KAT-verified on-device (r7)
__device__ uint2 tf2x32(uint2 k, uint32_t x0, uint32_t x1) {
  uint32_t ks0 = k.x, ks1 = k.y, ks2 = 0x1BD11BDAu ^ ks0 ^ ks1;
  x0 += ks0; x1 += ks1;
#define TF4(a,b,c,d) \
  x0 += x1; x1 = rotl32(x1,(a)); x1 ^= x0; \
  x0 += x1; x1 = rotl32(x1,(b)); x1 ^= x0; \
  x0 += x1; x1 = rotl32(x1,(c)); x1 ^= x0; \
  x0 += x1; x1 = rotl32(x1,(d)); x1 ^= x0;
  TF4(13,15,26,6)  x0 += ks1; x1 += ks2 + 1u;
  TF4(17,29,16,24) x0 += ks2; x1 += ks0 + 2u;
  TF4(13,15,26,6)  x0 += ks0; x1 += ks1 + 3u;
  TF4(17,29,16,24) x0 += ks1; x1 += ks2 + 4u;
  TF4(13,15,26,6)  x0 += ks2; x1 += ks0 + 5u;
#undef TF4
  return make_uint2(x0, x1);
}

// JAX uniform -> gumbel, bit-exact (verified vs ref arcs, r19)
__device__ __forceinline__ float gumbelf(uint32_t bits) {
  float f = __uint_as_float((bits >> 9) | 0x3f800000u) - 1.0f;
  const float tiny = 1.17549435082228751e-38f;
  float u = fmaxf(tiny, f);
  return -logf(-logf(u));
}

// XLA LogisticExpander form
__device__ __forceinline__ float sigm(float x) {
  return 0.5f + 0.5f * tanhf(0.5f * x);
}

__global__ void __launch_bounds__(TPB) ENAScontroller_21706764714567_kernel(
    const float* __restrict__ enc,   const float* __restrict__ Wih,
    const float* __restrict__ Whh,   const float* __restrict__ bih,
    const float* __restrict__ bhh,   const float* __restrict__ wsoft,
    const float* __restrict__ bsoft, const float* __restrict__ wa1,
    const float* __restrict__ wa2,   const float* __restrict__ vattn,
    float* __restrict__ out)
{
  const int b    = blockIdx.x;
  const int t    = threadIdx.x;
  const int lane = t & 63;
  const int wv_  = t >> 6;            // wave id 0..3

  unsigned hgen = 0;                  // uniform across all blocks/threads
  unsigned pgen = 0;

  // ---- LDS (~55 KB) ----
  __shared__ float4 sWhh4[64 * NROW]; // 32 KB
  __shared__ float4 sWa1p[64 * HS];   // 8 KB (own wa1 rows)
  __shared__ float4 sWa2p[64 * HS];   // 8 KB (own wa2 rows)
  __shared__ __align__(16) float s_h[D];
  __shared__ float s_part[TPB];
  __shared__ float s_pp[NB * 16];     // gathered attention partials
  __shared__ float s_eW[9][NROW];
  __shared__ float s_aW[MAXA][NROW];
  __shared__ float s_aw1[MAXA][HS];   // own aw1 slice
  __shared__ float s_t2[HS];
  __shared__ float s_vs[HS];
  __shared__ float s_c[HS];
  __shared__ float s_bc[NROW];
  __shared__ float s_bsoft[8];
  __shared__ float s_log[16];
  __shared__ float s_z[16];
  __shared__ uint2 s_pair[2];
  __shared__ uint2 s_key;
  __shared__ int   s_sel;
  __shared__ float s_lp, s_ent;

  // ---------- init ----------
  for (int idx = t; idx < 64 * NROW; idx += TPB) {
    int kk = idx >> 5, j = idx & 31;
    int grow = (j >> 3) * D + b * HS + (j & 7);
    sWhh4[idx] = *(const float4*)&Whh[grow * D + kk * 4];
  }
  for (int idx = t; idx < 64 * HS; idx += TPB) {
    int kk = idx >> 3, j = idx & 7;
    sWa1p[idx] = *(const float4*)&wa1[(b * HS + j) * D + kk * 4];
    sWa2p[idx] = *(const float4*)&wa2[(b * HS + j) * D + kk * 4];
  }
  if (t < NROW) {
    int grow = (t >> 3) * D + b * HS + (t & 7);
    s_bc[t] = bih[grow] + bhh[grow];
  }
  if (t < HS) {
    s_vs[t] = vattn[b * HS + t];
    s_c[t] = 0.f;
  }
  if (t < 8) s_bsoft[t] = bsoft[t];
  s_h[t] = 0.f;                       // h0 = 0 locally
  if (t == 0) { s_lp = 0.f; s_ent = 0.f; }
  // PARTITIONABLE split(key(123)): newkey[i] = cipher(key, (0, i))
  if (t < 2) s_pair[t] = tf2x32(make_uint2(0u, 123u), 0u, (uint32_t)t);
  __syncthreads();
  const uint2 key1 = s_pair[0];
  const uint2 key2 = s_pair[1];

  for (int m = 0; m < 8; ++m) {
    int j = wv_ * 8 + m;
    int grow = wv_ * D + b * HS + m;
    float4 wrow = *(const float4*)&Wih[grow * D + lane * 4];
    for (int r = 0; r < 9; ++r) {
      float4 ev = *(const float4*)&enc[r * D + lane * 4];
      float x = wrow.x * ev.x + wrow.y * ev.y + wrow.z * ev.z + wrow.w * ev.w;
      #pragma unroll
      for (int s = 32; s; s >>= 1) x += __shfl_xor(x, s);
      if (lane == 0) s_eW[r][j] = x;
    }
  }
  __syncthreads();

  // LSTM split: PRE = matvec(old h)+gates+qstore; POST = parallel 1-slot poll
  auto LSTM_PRE = [&](const float* xd) {
    {
      int j = t & 31, p = t >> 5;
      const float4* hp = (const float4*)s_h;
      float acc = 0.f;
      #pragma unroll
      for (int q = 0; q < 8; ++q) {
        int kk = p * 8 + q;
        float4 wvv = sWhh4[kk * 32 + j];
        float4 hv  = hp[kk];
        acc += wvv.x * hv.x + wvv.y * hv.y + wvv.z * hv.z + wvv.w * hv.w;
      }
      s_part[t] = acc;
    }
    __syncthreads();
    ++hgen;
    if (t < HS) {
      float gg[4];
      #pragma unroll
      for (int q = 0; q < 4; ++q) {
        int j = q * 8 + t;
        float s = s_bc[j] + xd[j];
        #pragma unroll
        for (int p = 0; p < 8; ++p) s += s_part[p * 32 + j];
        gg[q] = s;
      }
      float c2 = sigm(gg[1]) * s_c[t] + sigm(gg[0]) * tanhf(gg[2]);
      float hn = sigm(gg[3]) * tanhf(c2);
      s_c[t] = c2;
      qstore(&g_Hq[(hgen & 1) * D + b * HS + t], hgen, hn);
    }
    // no barrier: hidden work below reads OLD s_h (safe: parity slots)
  };

  auto LSTM_POST = [&]() {
    __syncthreads();                  // everyone done reading old s_h
    float hv = qpoll(&g_Hq[(hgen & 1) * D + t], hgen);   // 1 slot/thread
    s_h[t] = hv;
    __syncthreads();
  };

  auto DOT8 = [&](const float4* M, float* dst) {   // dst[j] = M_rows . s_h
    if (t < 64) {
      int j = t & 7, p = t >> 3;
      const float4* hp = (const float4*)s_h;
      float acc = 0.f;
      #pragma unroll
      for (int q = 0; q < 8; ++q) {
        int kk = p * 8 + q;
        float4 m4 = M[kk * 8 + j];
        float4 hv = hp[kk];
        acc += m4.x * hv.x + m4.y * hv.y + m4.z * hv.z + m4.w * hv.w;
      }
      s_part[t] = acc;
    }
    __syncthreads();
    if (t < 8) {
      float s = 0.f;
      #pragma unroll
      for (int p = 0; p < 8; ++p) s += s_part[p * 8 + t];
      dst[t] = s;
    }
    __syncthreads();
  };

  auto AWC = [&](int slot) {   // own W_ih rows @ s_h (anchor) — hidden work
    const float4* hp = (const float4*)s_h;
    for (int m = 0; m < 8; ++m) {
      int j = wv_ * 8 + m;
      int grow = wv_ * D + b * HS + m;
      float4 wrow = *(const float4*)&Wih[grow * D + lane * 4];
      float4 hv = hp[lane];
      float x = wrow.x * hv.x + wrow.y * hv.y + wrow.z * hv.z + wrow.w * hv.w;
      #pragma unroll
      for (int s = 32; s; s >>= 1) x += __shfl_xor(x, s);
      if (lane == 0) s_aW[slot][j] = x;
    }
    __syncthreads();
  };

  // attention: own-slice t2, own 14 partials -> exchange -> parallel gather
  auto ATTN = [&]() {
    DOT8(sWa2p, s_t2);
    ++pgen;
    if (t < MAXA) {
      float pa = 0.f;
      #pragma unroll
      for (int d2 = 0; d2 < HS; ++d2)
        pa += tanhf(s_aw1[t][d2] + s_t2[d2]) * s_vs[d2];
      qstore(&g_PartQ[(pgen & 1) * (NB * 16) + b * 16 + t], pgen, pa);
    }
    {
      unsigned long long* base2 = &g_PartQ[(pgen & 1) * (NB * 16)];
      #pragma unroll
      for (int s = t; s < NB * 16; s += TPB)          // 2 slots/thread
        if ((s & 15) < MAXA) s_pp[s] = qpoll(&base2[s], pgen);
    }
    __syncthreads();
  };

  auto ALOGITS = [&](int u) {
    if (t < MAXA) {
      float l = 0.f;
      #pragma unroll
      for (int bb = 0; bb < NB; ++bb) l += s_pp[bb * 16 + t];
      l = 1.1f * tanhf(l / 5.0f);
      s_log[t] = (t < u) ? l : NEGV;
    }
    __syncthreads();
  };

  auto OLOGITS = [&](bool useBias) {
    if (t < 64) {
      int j = t & 7, p = t >> 3;
      const float4* hp = (const float4*)s_h;
      float acc = 0.f;
      #pragma unroll
      for (int q = 0; q < 8; ++q) {
        int kk = p * 8 + q;
        float4 m4 = *(const float4*)&wsoft[j * D + kk * 4];
        float4 hv = hp[kk];
        acc += m4.x * hv.x + m4.y * hv.y + m4.z * hv.z + m4.w * hv.w;
      }
      s_part[t] = acc;
    }
    __syncthreads();
    if (t < 8) {
      float s = 0.f;
      #pragma unroll
      for (int p = 0; p < 8; ++p) s += s_part[p * 8 + t];
      float l = s + s_bsoft[t];
      l = 1.1f * tanhf(l / 5.0f);
      if (useBias) l += (t < 2 ? 0.25f : -0.25f);
      s_log[t] = l;
    }
    __syncthreads();
  };

  // PARTITIONABLE sampling — verified bit-exact vs reference arcs (r19)
  auto SAMPLE = [&](int N) -> int {
    if (t < 2) s_pair[t] = tf2x32(s_key, 0u, (uint32_t)t);
    __syncthreads();
    uint2 sub = s_pair[1];
    if (t == 0) s_key = s_pair[0];
    if (t < N) {
      uint2 e = tf2x32(sub, 0u, (uint32_t)t);
      s_z[t] = s_log[t] + gumbelf(e.x ^ e.y);
    }
    __syncthreads();
    if (t == 0) {
      int bi = 0; float bz = s_z[0];
      for (int a = 1; a < N; ++a) if (s_z[a] > bz) { bz = s_z[a]; bi = a; }
      float m = s_log[0];
      for (int a = 1; a < N; ++a) m = fmaxf(m, s_log[a]);
      float ssum = 0.f, sdl = 0.f;
      for (int a = 0; a < N; ++a) {
        float d2 = s_log[a] - m;
        float e2 = expf(d2);
        ssum += e2; sdl += e2 * d2;
      }
      float ls = logf(ssum);
      s_lp  += -(s_log[bi] - m - ls);
      s_ent += ls - sdl / ssum;
      s_sel = bi;
    }
    __syncthreads();
    return s_sel;
  };

  // ---------- two samplers ----------
  for (int smp = 0; smp < 2; ++smp) {
    for (int idx = t; idx < MAXA * NROW; idx += TPB) (&s_aW[0][0])[idx]  = 0.f;
    for (int idx = t; idx < MAXA * HS;   idx += TPB) (&s_aw1[0][0])[idx] = 0.f;
    if (t == 0) s_key = (smp == 0) ? key1 : key2;
    __syncthreads();

    // seeds (aw1[0] from h-after-seed1, hidden under seed-2's exchange)
    LSTM_PRE(s_eW[0]);
    LSTM_POST();
    LSTM_PRE(s_eW[0]);
    DOT8(sWa1p, s_aw1[0]);            // hidden: reads pre-exchange s_h
    LSTM_POST();

    bool useBias = (smp == 0);
    for (int u = 2; u < 2 + UNITS; ++u) {
      // anchor work hidden under the unit's first exchange
      LSTM_PRE(s_eW[0]);
      DOT8(sWa1p, s_aw1[u - 1]);      // hidden (pre-exchange s_h = anchor h)
      if (u > 2) AWC(u - 1);          // hidden
      LSTM_POST();

      ATTN(); ALOGITS(u);
      int i1 = SAMPLE(MAXA);
      LSTM_PRE(s_aW[i1]); LSTM_POST();

      ATTN(); ALOGITS(u);
      int i2 = SAMPLE(MAXA);
      LSTM_PRE(s_aW[i2]); LSTM_POST();

      OLOGITS(useBias);
      int o1 = SAMPLE(8);
      LSTM_PRE(s_eW[o1 + 1]); LSTM_POST();

      OLOGITS(useBias);
      int o2 = SAMPLE(8);
      LSTM_PRE(s_eW[o2 + 1]); LSTM_POST();

      if (b == 0 && t == 0) {
        int base = smp * 48 + (u - 2) * 4;
        out[base + 0] = (float)i1;   // harness reads float32 (r19)
        out[base + 1] = (float)o1;
        out[base + 2] = (float)i2;
        out[base + 3] = (float)o2;
      }
    }
  }
  if (b == 0 && t == 0) {
    out[96] = s_lp;
    out[97] = s_ent;
  }
}

extern "C" __attribute__((visibility("default")))
void kernel_launch(void* const* d_in, const int* in_sizes, int n_in,
                   void* d_out, int out_size, void* d_ws, size_t ws_size,
                   hipStream_t stream) {
  const float* enc   = (const float*)d_in[0];
  const float* Wih   = (const float*)d_in[1];
  const float* Whh   = (const float*)d_in[2];
  const float* bih   = (const float*)d_in[3];
  const float* bhh   = (const float*)d_in[4];
  const float* wsoft = (const float*)d_in[5];
  const float* bsoft = (const float*)d_in[6];
  const float* wa1   = (const float*)d_in[7];
  const float* wa2   = (const float*)d_in[8];
  const float* vattn = (const float*)d_in[9];
  float* out = (float*)d_out;

  init_kernel<<<dim3(1), dim3(1024), 0, stream>>>();
  ENAScontroller_21706764714567_kernel<<<dim3(NB), dim3(TPB), 0, stream>>>(
      enc, Wih, Whh, bih, bhh, wsoft, bsoft, wa1, wa2, vattn, out);
}

// Round 28
// 567.324 us; speedup vs baseline: 1.8528x; 1.0402x over previous
//
#include <hip/hip_runtime.h>
#include <cstdint>

#define D     256
#define NB    32          // blocks
#define TPB   256         // threads per block
#define HS    8           // h-elements owned per block (D/NB)
#define NROW  32          // gate rows owned per block (4*HS)
#define MAXA  14
#define UNITS 12
#define NEGV  (-1e9f)

// ---- cross-block state: gen-parity double-buffered self-tagged qwords ----
__device__ unsigned long long g_Hq[2 * D];        // h slots
__device__ unsigned long long g_PartQ[2 * NB*16]; // attention partial slots

__global__ void init_kernel() {
  int i = threadIdx.x;
  if (i < 2 * D) g_Hq[i] = 0ull;
  if (i < 2 * NB * 16) g_PartQ[i] = 0ull;
}

__device__ __forceinline__ void qstore(unsigned long long* p, unsigned gen,
                                       float v) {
  unsigned long long q =
      ((unsigned long long)gen << 32) | (unsigned long long)__float_as_uint(v);
  __hip_atomic_store(p, q, __ATOMIC_RELAXED, __HIP_MEMORY_SCOPE_AGENT);
}

__device__ __forceinline__ float qpoll(unsigned long long* p, unsigned gen) {
  unsigned long long q;
  long spins = 0;
  for (;;) {
    q = __hip_atomic_load(p, __ATOMIC_RELAXED, __HIP_MEMORY_SCOPE_AGENT);
    if ((unsigned)(q >> 32) == gen) break;
    __builtin_amdgcn_s_sleep(1);
    if (++spins > 20000000L) break;   // bail only on bug
  }
  return __uint_as_float((unsigned)q);
}

__device__ __forceinline__ uint32_t rotl32(uint32_t v, uint32_t n) {
  return (v << n) | (v >> (32u - n));
}

// JAX threefry2x32 (20 rounds) — KAT-verified on-device (r7)
__device__ uint2 tf2x32(uint2 k, uint32_t x0, uint32_t x1) {
  uint32_t ks0 = k.x, ks1 = k.y, ks2 = 0x1BD11BDAu ^ ks0 ^ ks1;
  x0 += ks0; x1 += ks1;
#define TF4(a,b,c,d) \
  x0 += x1; x1 = rotl32(x1,(a)); x1 ^= x0; \
  x0 += x1; x1 = rotl32(x1,(b)); x1 ^= x0; \
  x0 += x1; x1 = rotl32(x1,(c)); x1 ^= x0; \
  x0 += x1; x1 = rotl32(x1,(d)); x1 ^= x0;
  TF4(13,15,26,6)  x0 += ks1; x1 += ks2 + 1u;
  TF4(17,29,16,24) x0 += ks2; x1 += ks0 + 2u;
  TF4(13,15,26,6)  x0 += ks0; x1 += ks1 + 3u;
  TF4(17,29,16,24) x0 += ks1; x1 += ks2 + 4u;
  TF4(13,15,26,6)  x0 += ks2; x1 += ks0 + 5u;
#undef TF4
  return make_uint2(x0, x1);
}

// JAX uniform -> gumbel, bit-exact (verified vs ref arcs, r19)
__device__ __forceinline__ float gumbelf(uint32_t bits) {
  float f = __uint_as_float((bits >> 9) | 0x3f800000u) - 1.0f;
  const float tiny = 1.17549435082228751e-38f;
  float u = fmaxf(tiny, f);
  return -logf(-logf(u));
}

// XLA LogisticExpander form
__device__ __forceinline__ float sigm(float x) {
  return 0.5f + 0.5f * tanhf(0.5f * x);
}

__global__ void __launch_bounds__(TPB) ENAScontroller_21706764714567_kernel(
    const float* __restrict__ enc,   const float* __restrict__ Wih,
    const float* __restrict__ Whh,   const float* __restrict__ bih,
    const float* __restrict__ bhh,   const float* __restrict__ wsoft,
    const float* __restrict__ bsoft, const float* __restrict__ wa1,
    const float* __restrict__ wa2,   const float* __restrict__ vattn,
    float* __restrict__ out)
{
  const int b    = blockIdx.x;
  const int t    = threadIdx.x;
  const int lane = t & 63;
  const int wv_  = t >> 6;            // wave id 0..3

  unsigned hgen = 0;                  // uniform across all blocks/threads
  unsigned pgen = 0;

  // ---- LDS (~58 KB) ----
  __shared__ float4 sWhh4[64 * NROW]; // 32 KB
  __shared__ float4 sWa1p[64 * HS];   // 8 KB (own wa1 rows)
  __shared__ float4 sWa2p[64 * HS];   // 8 KB (own wa2 rows)
  __shared__ __align__(16) float s_h[D];
  __shared__ float s_part[TPB];       // DOT8 scratch
  __shared__ float s_mv[TPB];         // W_hh@h matvec partials (hoisted)
  __shared__ float s_pp[NB * 16];     // gathered attention partials
  __shared__ float s_eW[9][NROW];
  __shared__ float s_aW[MAXA][NROW];
  __shared__ float s_aw1[MAXA][HS];   // own aw1 slice
  __shared__ float s_t2[HS];
  __shared__ float s_vs[HS];
  __shared__ float s_c[HS];
  __shared__ float s_bc[NROW];
  __shared__ float s_bsoft[8];
  __shared__ float s_log[16];
  __shared__ float s_z[16];
  __shared__ uint2 s_pair[2];
  __shared__ uint2 s_key;
  __shared__ int   s_sel;
  __shared__ float s_lp, s_ent;

  // ---------- init ----------
  for (int idx = t; idx < 64 * NROW; idx += TPB) {
    int kk = idx >> 5, j = idx & 31;
    int grow = (j >> 3) * D + b * HS + (j & 7);
    sWhh4[idx] = *(const float4*)&Whh[grow * D + kk * 4];
  }
  for (int idx = t; idx < 64 * HS; idx += TPB) {
    int kk = idx >> 3, j = idx & 7;
    sWa1p[idx] = *(const float4*)&wa1[(b * HS + j) * D + kk * 4];
    sWa2p[idx] = *(const float4*)&wa2[(b * HS + j) * D + kk * 4];
  }
  if (t < NROW) {
    int grow = (t >> 3) * D + b * HS + (t & 7);
    s_bc[t] = bih[grow] + bhh[grow];
  }
  if (t < HS) {
    s_vs[t] = vattn[b * HS + t];
    s_c[t] = 0.f;
  }
  if (t < 8) s_bsoft[t] = bsoft[t];
  s_h[t] = 0.f;                       // h0 = 0 locally
  if (t == 0) { s_lp = 0.f; s_ent = 0.f; }
  // PARTITIONABLE split(key(123)): newkey[i] = cipher(key, (0, i))
  if (t < 2) s_pair[t] = tf2x32(make_uint2(0u, 123u), 0u, (uint32_t)t);
  __syncthreads();
  const uint2 key1 = s_pair[0];
  const uint2 key2 = s_pair[1];

  for (int m = 0; m < 8; ++m) {
    int j = wv_ * 8 + m;
    int grow = wv_ * D + b * HS + m;
    float4 wrow = *(const float4*)&Wih[grow * D + lane * 4];
    for (int r = 0; r < 9; ++r) {
      float4 ev = *(const float4*)&enc[r * D + lane * 4];
      float x = wrow.x * ev.x + wrow.y * ev.y + wrow.z * ev.z + wrow.w * ev.w;
      #pragma unroll
      for (int s = 32; s; s >>= 1) x += __shfl_xor(x, s);
      if (lane == 0) s_eW[r][j] = x;
    }
  }
  __syncthreads();

  // x-independent half of LSTM: s_mv = W_hh @ s_h partials
  auto MATVEC = [&]() {
    int j = t & 31, p = t >> 5;
    const float4* hp = (const float4*)s_h;
    float acc = 0.f;
    #pragma unroll
    for (int q = 0; q < 8; ++q) {
      int kk = p * 8 + q;
      float4 wvv = sWhh4[kk * 32 + j];
      float4 hv  = hp[kk];
      acc += wvv.x * hv.x + wvv.y * hv.y + wvv.z * hv.z + wvv.w * hv.w;
    }
    s_mv[t] = acc;
    __syncthreads();
  };

  // x-dependent half: gates + qstore (8 threads); no trailing barrier
  auto GATES = [&](const float* xd) {
    ++hgen;
    if (t < HS) {
      float gg[4];
      #pragma unroll
      for (int q = 0; q < 4; ++q) {
        int j = q * 8 + t;
        float s = s_bc[j] + xd[j];
        #pragma unroll
        for (int p = 0; p < 8; ++p) s += s_mv[p * 32 + j];
        gg[q] = s;
      }
      float c2 = sigm(gg[1]) * s_c[t] + sigm(gg[0]) * tanhf(gg[2]);
      float hn = sigm(gg[3]) * tanhf(c2);
      s_c[t] = c2;
      qstore(&g_Hq[(hgen & 1) * D + b * HS + t], hgen, hn);
    }
  };

  auto LSTM_POST = [&]() {
    __syncthreads();                  // everyone done reading old s_h / s_mv
    float hv = qpoll(&g_Hq[(hgen & 1) * D + t], hgen);   // 1 slot/thread
    s_h[t] = hv;
    __syncthreads();
  };

  auto DOT8 = [&](const float4* M, float* dst) {   // dst[j] = M_rows . s_h
    if (t < 64) {
      int j = t & 7, p = t >> 3;
      const float4* hp = (const float4*)s_h;
      float acc = 0.f;
      #pragma unroll
      for (int q = 0; q < 8; ++q) {
        int kk = p * 8 + q;
        float4 m4 = M[kk * 8 + j];
        float4 hv = hp[kk];
        acc += m4.x * hv.x + m4.y * hv.y + m4.z * hv.z + m4.w * hv.w;
      }
      s_part[t] = acc;
    }
    __syncthreads();
    if (t < 8) {
      float s = 0.f;
      #pragma unroll
      for (int p = 0; p < 8; ++p) s += s_part[p * 8 + t];
      dst[t] = s;
    }
    __syncthreads();
  };

  auto AWC = [&](int slot) {   // own W_ih rows @ s_h (anchor) — hidden work
    const float4* hp = (const float4*)s_h;
    for (int m = 0; m < 8; ++m) {
      int j = wv_ * 8 + m;
      int grow = wv_ * D + b * HS + m;
      float4 wrow = *(const float4*)&Wih[grow * D + lane * 4];
      float4 hv = hp[lane];
      float x = wrow.x * hv.x + wrow.y * hv.y + wrow.z * hv.z + wrow.w * hv.w;
      #pragma unroll
      for (int s = 32; s; s >>= 1) x += __shfl_xor(x, s);
      if (lane == 0) s_aW[slot][j] = x;
    }
    __syncthreads();
  };

  // partial compute+store (no trailing barrier; t2 covered by DOT8's barrier)
  auto PSTORE = [&]() {
    ++pgen;
    if (t < MAXA) {
      float pa = 0.f;
      #pragma unroll
      for (int d2 = 0; d2 < HS; ++d2)
        pa += tanhf(s_aw1[t][d2] + s_t2[d2]) * s_vs[d2];
      qstore(&g_PartQ[(pgen & 1) * (NB * 16) + b * 16 + t], pgen, pa);
    }
  };

  auto PGATHER = [&]() {
    unsigned long long* base2 = &g_PartQ[(pgen & 1) * (NB * 16)];
    #pragma unroll
    for (int s = t; s < NB * 16; s += TPB)
      if ((s & 15) < MAXA) s_pp[s] = qpoll(&base2[s], pgen);
    __syncthreads();
  };

  auto ALOGITS = [&](int u) {
    if (t < MAXA) {
      float l = 0.f;
      #pragma unroll
      for (int bb = 0; bb < NB; ++bb) l += s_pp[bb * 16 + t];
      l = 1.1f * tanhf(l / 5.0f);
      s_log[t] = (t < u) ? l : NEGV;
    }
    __syncthreads();
  };

  auto OLOGITS = [&](bool useBias) {
    if (t < 64) {
      int j = t & 7, p = t >> 3;
      const float4* hp = (const float4*)s_h;
      float acc = 0.f;
      #pragma unroll
      for (int q = 0; q < 8; ++q) {
        int kk = p * 8 + q;
        float4 m4 = *(const float4*)&wsoft[j * D + kk * 4];
        float4 hv = hp[kk];
        acc += m4.x * hv.x + m4.y * hv.y + m4.z * hv.z + m4.w * hv.w;
      }
      s_part[t] = acc;
    }
    __syncthreads();
    if (t < 8) {
      float s = 0.f;
      #pragma unroll
      for (int p = 0; p < 8; ++p) s += s_part[p * 8 + t];
      float l = s + s_bsoft[t];
      l = 1.1f * tanhf(l / 5.0f);
      if (useBias) l += (t < 2 ? 0.25f : -0.25f);
      s_log[t] = l;
    }
    __syncthreads();
  };

  // PARTITIONABLE sampling — verified bit-exact vs reference arcs (r19)
  auto SAMPLE = [&](int N) -> int {
    if (t < 2) s_pair[t] = tf2x32(s_key, 0u, (uint32_t)t);
    __syncthreads();
    uint2 sub = s_pair[1];
    if (t == 0) s_key = s_pair[0];
    if (t < N) {
      uint2 e = tf2x32(sub, 0u, (uint32_t)t);
      s_z[t] = s_log[t] + gumbelf(e.x ^ e.y);
    }
    __syncthreads();
    if (t == 0) {
      int bi = 0; float bz = s_z[0];
      for (int a = 1; a < N; ++a) if (s_z[a] > bz) { bz = s_z[a]; bi = a; }
      float m = s_log[0];
      for (int a = 1; a < N; ++a) m = fmaxf(m, s_log[a]);
      float ssum = 0.f, sdl = 0.f;
      for (int a = 0; a < N; ++a) {
        float d2 = s_log[a] - m;
        float e2 = expf(d2);
        ssum += e2; sdl += e2 * d2;
      }
      float ls = logf(ssum);
      s_lp  += -(s_log[bi] - m - ls);
      s_ent += ls - sdl / ssum;
      s_sel = bi;
    }
    __syncthreads();
    return s_sel;
  };

  // ---------- two samplers ----------
  for (int smp = 0; smp < 2; ++smp) {
    for (int idx = t; idx < MAXA * NROW; idx += TPB) (&s_aW[0][0])[idx]  = 0.f;
    for (int idx = t; idx < MAXA * HS;   idx += TPB) (&s_aw1[0][0])[idx] = 0.f;
    if (t == 0) s_key = (smp == 0) ? key1 : key2;
    __syncthreads();

    // seeds (aw1[0] from h-after-seed1, hidden under seed-2's exchange)
    MATVEC(); GATES(s_eW[0]);
    LSTM_POST();
    MATVEC(); GATES(s_eW[0]);
    DOT8(sWa1p, s_aw1[0]);            // hidden: reads pre-exchange s_h
    LSTM_POST();

    bool useBias = (smp == 0);
    for (int u = 2; u < 2 + UNITS; ++u) {
      // unit-start LSTM (x = enc[0]); anchor work hidden under exchange
      MATVEC(); GATES(s_eW[0]);
      DOT8(sWa1p, s_aw1[u - 1]);      // hidden (pre-exchange s_h = anchor h)
      if (u > 2) AWC(u - 1);          // hidden
      LSTM_POST();

      // i1: matvec hoisted under partial-exchange flight
      DOT8(sWa2p, s_t2);
      PSTORE();
      MATVEC();                       // hidden under partial RTT
      PGATHER(); ALOGITS(u);
      int i1 = SAMPLE(MAXA);
      GATES(s_aW[i1]);
      LSTM_POST();

      // i2
      DOT8(sWa2p, s_t2);
      PSTORE();
      MATVEC();                       // hidden under partial RTT
      PGATHER(); ALOGITS(u);
      int i2 = SAMPLE(MAXA);
      GATES(s_aW[i2]);
      LSTM_POST();

      // o1
      OLOGITS(useBias);
      MATVEC();
      int o1 = SAMPLE(8);
      GATES(s_eW[o1 + 1]);
      LSTM_POST();

      // o2
      OLOGITS(useBias);
      MATVEC();
      int o2 = SAMPLE(8);
      GATES(s_eW[o2 + 1]);
      LSTM_POST();

      if (b == 0 && t == 0) {
        int base = smp * 48 + (u - 2) * 4;
        out[base + 0] = (float)i1;   // harness reads float32 (r19)
        out[base + 1] = (float)o1;
        out[base + 2] = (float)i2;
        out[base + 3] = (float)o2;
      }
    }
  }
  if (b == 0 && t == 0) {
    out[96] = s_lp;
    out[97] = s_ent;
  }
}

extern "C" __attribute__((visibility("default")))
void kernel_launch(void* const* d_in, const int* in_sizes, int n_in,
                   void* d_out, int out_size, void* d_ws, size_t ws_size,
                   hipStream_t stream) {
  const float* enc   = (const float*)d_in[0];
  const float* Wih   = (const float*)d_in[1];
  const float* Whh   = (const float*)d_in[2];
  const float* bih   = (const float*)d_in[3];
  const float* bhh   = (const float*)d_in[4];
  const float* wsoft = (const float*)d_in[5];
  const float* bsoft = (const float*)d_in[6];
  const float* wa1   = (const float*)d_in[7];
  const float* wa2   = (const float*)d_in[8];
  const float* vattn = (const float*)d_in[9];
  float* out = (float*)d_out;

  init_kernel<<<dim3(1), dim3(1024), 0, stream>>>();
  ENAScontroller_21706764714567_kernel<<<dim3(NB), dim3(TPB), 0, stream>>>(
      enc, Wih, Whh, bih, bhh, wsoft, bsoft, wa1, wa2, vattn, out);
}